// Round 3
// baseline (153.574 us; speedup 1.0000x reference)
//
#include <hip/hip_runtime.h>
#include <math.h>

#define QD 24
#define KD 24
#define HD 64
#define NN 512
#define DO 128
#define BT 512

__device__ __forceinline__ float fast_tanh(float x) {
    // tanh(x) = sign(x) * (1 - e^{-2|x|}) / (1 + e^{-2|x|}); exp via exp2
    float ax = __builtin_fabsf(x);
    float t  = __builtin_amdgcn_exp2f(-2.885390081777927f * ax); // -2*log2(e)*|x|
    float r  = (1.0f - t) * __builtin_amdgcn_rcpf(1.0f + t);
    return __builtin_copysignf(r, x);
}

// One 512-thread block per batch row b.
//  - Q-path (Linear-Tanh-Linear) fused, K-layer-2 folded into qks = wk2 @ q
//    (bk2 adds a per-row constant -> cancels in softmax; scale*log2e folded).
//  - Each thread computes ONE score row (n = t): 24x64 fma + tanh + dot.
//  - Softmax shift = fixed bound Mb = sum|qks| (|tanh|<=1 => s <= Mb): no max
//    reduction, exact by shift-invariance.
//  - All 8 waves then stream TO (537 MB total) with deep unroll.
// Overlap across blocks: 2 blocks/CU, 4 generations -> score VALU of one
// block hides under the TO stream of its co-resident neighbor.
__global__ __launch_bounds__(BT, 4) void fused_attn(
    const float* __restrict__ fwp,   // [B, 24]
    const float* __restrict__ pwp,   // [B, N, 24]
    const float* __restrict__ to,    // [B, N, 128]
    const float* __restrict__ wq1, const float* __restrict__ bq1,
    const float* __restrict__ wq2, const float* __restrict__ bq2,
    const float* __restrict__ wk1, const float* __restrict__ bk1,
    const float* __restrict__ wk2,
    float* __restrict__ out_ctx,     // [B, 128]
    float* __restrict__ out_attn)    // [B, N]
{
    const int b = blockIdx.x;
    const int t = threadIdx.x;

    __shared__ float xf[QD];
    __shared__ float h1[HD];
    __shared__ float qv[HD];
    __shared__ float qks[HD];        // wk2 @ q, pre-scaled by 0.125*log2(e)
    __shared__ float p_all[NN];
    __shared__ float s_red[8];
    __shared__ float4 part[16][32];

    // Issue this thread's pwp row loads immediately; they complete under the
    // Q-path prologue barriers.
    const float* prow = pwp + ((size_t)b * NN + t) * KD;
    float4 xv0 = reinterpret_cast<const float4*>(prow)[0];
    float4 xv1 = reinterpret_cast<const float4*>(prow)[1];
    float4 xv2 = reinterpret_cast<const float4*>(prow)[2];
    float4 xv3 = reinterpret_cast<const float4*>(prow)[3];
    float4 xv4 = reinterpret_cast<const float4*>(prow)[4];
    float4 xv5 = reinterpret_cast<const float4*>(prow)[5];

    // ---------- Q-path + fold of K-layer-2 ----------
    if (t < QD) xf[t] = fwp[(size_t)b * QD + t];
    __syncthreads();
    if (t < HD) {
        float a = bq1[t];
#pragma unroll
        for (int k = 0; k < QD; ++k) a = fmaf(xf[k], wq1[k * HD + t], a);
        h1[t] = fast_tanh(a);
    }
    __syncthreads();
    if (t < HD) {
        float a = bq2[t];
#pragma unroll
        for (int i = 0; i < HD; ++i) a = fmaf(h1[i], wq2[i * HD + t], a);
        qv[t] = a;
    }
    __syncthreads();
    if (t < HD) {
        float s = 0.0f;
#pragma unroll
        for (int h = 0; h < HD; ++h) s = fmaf(wk2[t * HD + h], qv[h], s);
        qks[t] = s * 0.18033688011112042f;   // (1/8) * log2(e)
    }
    __syncthreads();

    float Mb = 0.0f;                 // fixed softmax shift (upper bound)
#pragma unroll
    for (int h = 0; h < HD; ++h) Mb += __builtin_fabsf(qks[h]);

    // ---------- score for row n = t ----------
    float x[KD];
    x[0]=xv0.x; x[1]=xv0.y; x[2]=xv0.z; x[3]=xv0.w;
    x[4]=xv1.x; x[5]=xv1.y; x[6]=xv1.z; x[7]=xv1.w;
    x[8]=xv2.x; x[9]=xv2.y; x[10]=xv2.z; x[11]=xv2.w;
    x[12]=xv3.x; x[13]=xv3.y; x[14]=xv3.z; x[15]=xv3.w;
    x[16]=xv4.x; x[17]=xv4.y; x[18]=xv4.z; x[19]=xv4.w;
    x[20]=xv5.x; x[21]=xv5.y; x[22]=xv5.z; x[23]=xv5.w;

    const float4* wk1_4 = reinterpret_cast<const float4*>(wk1);
    const float4* bk1_4 = reinterpret_cast<const float4*>(bk1);
    const float4* qks_4 = reinterpret_cast<const float4*>(qks);

    float sc = 0.0f;
#pragma unroll 2
    for (int j4 = 0; j4 < HD / 4; ++j4) {
        float4 bb = bk1_4[j4];                 // uniform -> scalar load
        float a0 = bb.x, a1 = bb.y, a2 = bb.z, a3 = bb.w;
#pragma unroll
        for (int k = 0; k < KD; ++k) {
            float4 w = wk1_4[k * (HD / 4) + j4];  // uniform -> scalar load
            a0 = fmaf(x[k], w.x, a0); a1 = fmaf(x[k], w.y, a1);
            a2 = fmaf(x[k], w.z, a2); a3 = fmaf(x[k], w.w, a3);
        }
        float4 qq = qks_4[j4];                 // LDS broadcast
        sc = fmaf(fast_tanh(a0), qq.x, sc);
        sc = fmaf(fast_tanh(a1), qq.y, sc);
        sc = fmaf(fast_tanh(a2), qq.z, sc);
        sc = fmaf(fast_tanh(a3), qq.w, sc);
    }
    const float p = __builtin_amdgcn_exp2f(sc - Mb);
    p_all[t] = p;

    // ---------- denominator (block reduce) ----------
    float l = p;
#pragma unroll
    for (int o = 32; o > 0; o >>= 1) l += __shfl_xor(l, o, 64);
    if ((t & 63) == 0) s_red[t >> 6] = l;
    __syncthreads();                 // also publishes p_all for the stream
    const float L = ((s_red[0] + s_red[1]) + (s_red[2] + s_red[3]))
                  + ((s_red[4] + s_red[5]) + (s_red[6] + s_red[7]));
    const float invL = __builtin_amdgcn_rcpf(L);
    out_attn[(size_t)b * NN + t] = p * invL;

    // ---------- stream TO: all 8 waves ----------
    const int g  = t & 31;           // float4 column 0..31
    const int np = t >> 5;           // row partition 0..15 (32 rows each)
    const float4* trow = reinterpret_cast<const float4*>(to + (size_t)b * NN * DO) + g;
    float4 acc = make_float4(0.f, 0.f, 0.f, 0.f);
#pragma unroll 8
    for (int i = 0; i < 32; ++i) {
        const int n = np * 32 + i;
        const float pp = p_all[n];   // half-wave broadcast, conflict-free
        float4 v = trow[(size_t)n * (DO / 4)];
        acc.x = fmaf(pp, v.x, acc.x);
        acc.y = fmaf(pp, v.y, acc.y);
        acc.z = fmaf(pp, v.z, acc.z);
        acc.w = fmaf(pp, v.w, acc.w);
    }
    part[np][g] = acc;
    __syncthreads();

    if (t < 32) {
        float4 r = part[0][t];
#pragma unroll
        for (int q = 1; q < 16; ++q) {
            float4 v = part[q][t];
            r.x += v.x; r.y += v.y; r.z += v.z; r.w += v.w;
        }
        float4 o;
        o.x = r.x * invL; o.y = r.y * invL; o.z = r.z * invL; o.w = r.w * invL;
        reinterpret_cast<float4*>(out_ctx + (size_t)b * DO)[t] = o;
    }
}

extern "C" void kernel_launch(void* const* d_in, const int* in_sizes, int n_in,
                              void* d_out, int out_size, void* d_ws, size_t ws_size,
                              hipStream_t stream) {
    const float* fwp = (const float*)d_in[0];
    const float* pwp = (const float*)d_in[1];
    const float* to  = (const float*)d_in[2];
    const float* wq1 = (const float*)d_in[3];
    const float* bq1 = (const float*)d_in[4];
    const float* wq2 = (const float*)d_in[5];
    const float* bq2 = (const float*)d_in[6];
    const float* wk1 = (const float*)d_in[7];
    const float* bk1 = (const float*)d_in[8];
    const float* wk2 = (const float*)d_in[9];
    // d_in[10] = bk2: per-row constant in scores -> cancels in softmax.

    float* out = (float*)d_out;
    const int B = in_sizes[0] / QD;  // 2048

    fused_attn<<<B, BT, 0, stream>>>(fwp, pwp, to, wq1, bq1, wq2, bq2,
                                     wk1, bk1, wk2,
                                     out, out + (size_t)B * DO);
}